// Round 5
// baseline (393.577 us; speedup 1.0000x reference)
//
#include <hip/hip_runtime.h>
#include <hip/hip_bf16.h>
#include <stdint.h>

#define T_STEPS 16
#define BATCH   16
#define CHANNELS 32
#define HGT 128
#define WID 128
#define HW (HGT*WID)      // 16384
#define KSEL 8192         // ascending 0-based rank of threshold = N - k
#define CAP 1024          // candidate buffer size (safety)
#define SMALL 64          // stop narrowing when candidate set <= SMALL

typedef float vfloat4 __attribute__((ext_vector_type(4)));
typedef float vfloat2 __attribute__((ext_vector_type(2)));

// ---------- kernel 1: channel max pool (memory-bound streamer) ----------
__global__ __launch_bounds__(256)
void pool_max_kernel(const float* __restrict__ x, float* __restrict__ pooled) {
    int tid  = blockIdx.x * blockDim.x + threadIdx.x;   // 1,048,576 threads
    int base = tid * 4;                                 // pooled element index
    int tb   = base >> 14;                              // /HW
    int pix  = base & (HW - 1);
    const vfloat4* src = (const vfloat4*)(x + (size_t)tb * CHANNELS * HW + pix);
    vfloat4 m = __builtin_nontemporal_load(src);
    #pragma unroll
    for (int c = 1; c < CHANNELS; ++c) {
        vfloat4 v = __builtin_nontemporal_load(src + (size_t)c * (HW/4));
        m.x = fmaxf(m.x, v.x); m.y = fmaxf(m.y, v.y);
        m.z = fmaxf(m.z, v.z); m.w = fmaxf(m.w, v.w);
    }
    *(vfloat4*)(pooled + base) = m;
}

// ---------- kernel 2: lif0 with exact linear-histogram select ----------
__global__ __launch_bounds__(1024)
void lif0_kernel(const float* __restrict__ pooled, uint8_t* __restrict__ spk) {
    __shared__ uint32_t hist[16][260];   // per-wave rows, padded
    __shared__ uint32_t s_tot[256];      // merged histogram
    __shared__ float    col[CAP];
    __shared__ uint32_t s_sel[4];        // jsel, r_new, cnt_new, collect-counter
    __shared__ float    s_thr;

    const int b    = blockIdx.x;
    const int tid  = threadIdx.x;
    const int wid  = tid >> 6;
    const int lane = tid & 63;
    uint32_t* hflat = &hist[0][0];

    float m[16];
    #pragma unroll
    for (int i = 0; i < 16; ++i) m[i] = 0.0f;

    for (int t = 0; t < T_STEPS; ++t) {
        // ---- integrate: mem = 0.25*mem + x  (bit-identical to ref) ----
        const float4* p4 = (const float4*)(pooled + ((size_t)t * BATCH + b) * HW);
        #pragma unroll
        for (int i = 0; i < 4; ++i) {
            float4 v = p4[i * 1024 + tid];
            m[i*4+0] = 0.25f * m[i*4+0] + v.x;
            m[i*4+1] = 0.25f * m[i*4+1] + v.y;
            m[i*4+2] = 0.25f * m[i*4+2] + v.z;
            m[i*4+3] = 0.25f * m[i*4+3] + v.w;
        }

        // ---- exact select of ascending-rank KSEL via linear histogram ----
        uint32_t amask = 0xFFFFu;        // alive (candidate) elements
        float    rlo   = 0.0f;           // values are max-of-32-normals: ~[0.5,4.5]
        float    scale = 32.0f;          // 256 bins over [0,8): width 1/32
        uint32_t r     = KSEL;           // target rank within alive set
        uint32_t cnt   = HW;
        int      iter  = 0;
        for (;;) {
            // clear histograms (16*260 = 4160 words)
            #pragma unroll
            for (int j = 0; j < 5; ++j) {
                int idx = tid + (j << 10);
                if (idx < 16 * 260) hflat[idx] = 0;
            }
            __syncthreads();
            // per-wave histogram of alive elements (linear value bins)
            #pragma unroll
            for (int i = 0; i < 16; ++i) {
                if (amask & (1u << i)) {
                    int bn = (int)((m[i] - rlo) * scale);
                    bn = min(max(bn, 0), 255);
                    atomicAdd(&hist[wid][bn], 1u);
                }
            }
            __syncthreads();
            // parallel merge: 256 threads x 16 reads
            if (tid < 256) {
                uint32_t s = 0;
                #pragma unroll
                for (int w = 0; w < 16; ++w) s += hist[w][tid];
                s_tot[tid] = s;
            }
            __syncthreads();
            // wave 0: scan 256 bins (4/lane), pick bin containing rank r
            if (wid == 0) {
                uint32_t c[4], lsum = 0;
                #pragma unroll
                for (int q = 0; q < 4; ++q) { c[q] = s_tot[lane * 4 + q]; lsum += c[q]; }
                uint32_t inc = lsum;
                #pragma unroll
                for (int off = 1; off < 64; off <<= 1) {
                    uint32_t v = __shfl_up(inc, off, 64);
                    if (lane >= off) inc += v;
                }
                uint32_t acc = inc - lsum;   // count below lane*4
                int dsel = -1; uint32_t nr = 0, nc = 0;
                #pragma unroll
                for (int q = 0; q < 4; ++q) {
                    if (dsel < 0 && r >= acc && r < acc + c[q]) {
                        dsel = lane * 4 + q; nr = r - acc; nc = c[q];
                    }
                    acc += c[q];
                }
                if (dsel >= 0) { s_sel[0] = (uint32_t)dsel; s_sel[1] = nr; s_sel[2] = nc; }
                if (tid == 0) s_sel[3] = 0;  // reset collect counter
            }
            __syncthreads();
            const int jsel = (int)s_sel[0];
            r   = s_sel[1];
            cnt = s_sel[2];
            // keep only elements in the selected bin (identical bin computation)
            #pragma unroll
            for (int i = 0; i < 16; ++i) {
                if (amask & (1u << i)) {
                    int bn = (int)((m[i] - rlo) * scale);
                    bn = min(max(bn, 0), 255);
                    if (bn != jsel) amask &= ~(1u << i);
                }
            }
            rlo   = rlo + (float)jsel / scale;
            scale = scale * 256.0f;
            if (cnt <= SMALL || ++iter >= 6) break;
        }

        // ---- collect candidates: wave scan + 1 atomic per wave ----
        {
            uint32_t myc  = (uint32_t)__popc((int)amask);
            uint32_t incl = myc;
            #pragma unroll
            for (int off = 1; off < 64; off <<= 1) {
                uint32_t v = __shfl_up(incl, off, 64);
                if (lane >= off) incl += v;
            }
            uint32_t wtot = __shfl(incl, 63, 64);
            uint32_t base = 0;
            if (lane == 63) base = atomicAdd(&s_sel[3], wtot);
            base = __shfl(base, 63, 64);
            uint32_t off = base + incl - myc;
            #pragma unroll
            for (int i = 0; i < 16; ++i) {
                if (amask & (1u << i)) {
                    if (off < CAP) col[off] = m[i];
                    ++off;
                }
            }
        }
        __syncthreads();
        // ---- exact rank-select among candidates (float compares) ----
        {
            uint32_t ncol = min(cnt, (uint32_t)CAP);
            for (uint32_t j = tid; j < ncol; j += 1024) {
                float v = col[j];
                uint32_t less = 0, leq = 0;
                for (uint32_t i = 0; i < ncol; ++i) {
                    float u = col[i];
                    less += (u < v);
                    leq  += (u <= v);
                }
                if (less <= r && r < leq) s_thr = v;   // k-th largest, exact bits
            }
        }
        __syncthreads();
        const float thr = s_thr;

        // ---- spikes + hard reset ----
        uchar4* so4 = (uchar4*)(spk + ((size_t)t * BATCH + b) * HW);
        #pragma unroll
        for (int i = 0; i < 4; ++i) {
            uchar4 s4;
            s4.x = (m[i*4+0] >= thr) ? 1 : 0;
            s4.y = (m[i*4+1] >= thr) ? 1 : 0;
            s4.z = (m[i*4+2] >= thr) ? 1 : 0;
            s4.w = (m[i*4+3] >= thr) ? 1 : 0;
            if (s4.x) m[i*4+0] = 0.0f;
            if (s4.y) m[i*4+1] = 0.0f;
            if (s4.z) m[i*4+2] = 0.0f;
            if (s4.w) m[i*4+3] = 0.0f;
            so4[i * 1024 + tid] = s4;
        }
        __syncthreads();   // protect LDS reuse next t
    }
}

// ---------- kernel 3: fused 7x7 conv (cross-correlation) + lif1 ----------
// 256 blocks = (b, 8-row stripe); thread computes a 1x4 output strip via
// sliding window: 7 rows x 10 cols LDS reads per 4 px (17.5/px vs 49/px).
__global__ __launch_bounds__(256)
void conv_lif1_kernel(const uint8_t* __restrict__ spk, const float* __restrict__ wconv,
                      float* __restrict__ out_spike, float* __restrict__ out_mem) {
    __shared__ float tile[14][136];  // 8-row stripe + 3 halo each side
    const int bidx   = blockIdx.x;   // 0..255
    const int b      = bidx >> 4;
    const int stripe = bidx & 15;
    const int r0     = stripe * 8;
    const int tid    = threadIdx.x;
    const int sr     = tid >> 5;           // 0..7
    const int c0     = (tid & 31) << 2;    // 0,4,...,124

    float w[49];
    #pragma unroll
    for (int i = 0; i < 49; ++i) w[i] = wconv[i];   // uniform -> scalar regs

    float mem[4] = {0.0f, 0.0f, 0.0f, 0.0f};

    for (int t = 0; t < T_STEPS; ++t) {
        __syncthreads();   // tile reuse guard
        const uint8_t* sp = spk + ((size_t)t * BATCH + b) * HW;
        for (int k = tid; k < 14 * 134; k += 256) {
            int row  = k / 134;
            int colp = k - row * 134;
            int gr = r0 - 3 + row;
            int gc = colp - 3;
            float v = 0.0f;
            if ((unsigned)gr < HGT && (unsigned)gc < WID)
                v = (float)sp[gr * WID + gc];
            tile[row][colp] = v;
        }
        __syncthreads();
        float a0 = 0.f, a1 = 0.f, a2 = 0.f, a3 = 0.f;
        #pragma unroll
        for (int dy = 0; dy < 7; ++dy) {
            const float* rowp = &tile[sr + dy][c0];
            vfloat4 u = *(const vfloat4*)rowp;        // 16B aligned (c0%4==0, stride 544B)
            vfloat4 v = *(const vfloat4*)(rowp + 4);
            vfloat2 e = *(const vfloat2*)(rowp + 8);
            float r[10] = {u.x,u.y,u.z,u.w, v.x,v.y,v.z,v.w, e.x,e.y};
            #pragma unroll
            for (int dx = 0; dx < 7; ++dx) {
                float wv = w[dy * 7 + dx];
                a0 = fmaf(r[dx + 0], wv, a0);
                a1 = fmaf(r[dx + 1], wv, a1);
                a2 = fmaf(r[dx + 2], wv, a2);
                a3 = fmaf(r[dx + 3], wv, a3);
            }
        }
        float m0 = 0.25f * mem[0] + a0;
        float m1 = 0.25f * mem[1] + a1;
        float m2 = 0.25f * mem[2] + a2;
        float m3 = 0.25f * mem[3] + a3;
        float s0 = (m0 > 1.0f) ? 1.0f : 0.0f;
        float s1 = (m1 > 1.0f) ? 1.0f : 0.0f;
        float s2 = (m2 > 1.0f) ? 1.0f : 0.0f;
        float s3 = (m3 > 1.0f) ? 1.0f : 0.0f;
        size_t o = (((size_t)t * BATCH + b) << 14) + (size_t)(r0 + sr) * WID + c0;
        vfloat4 sv = {s0, s1, s2, s3};
        vfloat4 mv = {m0, m1, m2, m3};
        *(vfloat4*)(out_spike + o) = sv;
        *(vfloat4*)(out_mem   + o) = mv;
        mem[0] = m0 - s0; mem[1] = m1 - s1; mem[2] = m2 - s2; mem[3] = m3 - s3;
    }
}

extern "C" void kernel_launch(void* const* d_in, const int* in_sizes, int n_in,
                              void* d_out, int out_size, void* d_ws, size_t ws_size,
                              hipStream_t stream) {
    const float* x     = (const float*)d_in[0];
    const float* wconv = (const float*)d_in[1];
    float* out = (float*)d_out;

    const size_t n_pooled = (size_t)T_STEPS * BATCH * HW;     // 4,194,304
    float*   pooled = (float*)d_ws;
    uint8_t* spk    = (uint8_t*)d_ws + n_pooled * sizeof(float);

    // TIMING INSTRUMENT: pool launched TWICE (pure function, idempotent result).
    // dur(this round) - dur(next round, single launch) = exact pool cost.
    pool_max_kernel<<<4096, 256, 0, stream>>>(x, pooled);
    pool_max_kernel<<<4096, 256, 0, stream>>>(x, pooled);
    lif0_kernel<<<BATCH, 1024, 0, stream>>>(pooled, spk);
    conv_lif1_kernel<<<256, 256, 0, stream>>>(spk, wconv, out, out + n_pooled);
}